// Round 5
// baseline (55.858 us; speedup 1.0000x reference)
//
#include <hip/hip_runtime.h>

typedef unsigned short u16;
typedef unsigned int u32;
typedef __attribute__((ext_vector_type(8))) __bf16 bf16x8;
typedef __attribute__((ext_vector_type(4))) __bf16 bf16x4;
typedef __attribute__((ext_vector_type(4))) float f32x4;

#define S_LEN 169
#define SP 192

// ---------------- workspace layout (bytes)
#define W2T_WS 0                         // bf16 [256][192] = 98304
#define KE_WS  98304                     // f32 [256][176][16] = 2883584
#define KV_WS  (98304 + 2883584)
#define SG_WS  (98304 + 2 * 2883584)

// ---------------- S kernel LDS
#define SKE  0
#define SKV  11264
#define SG2  22528
#define SKVT 33792
#define SRB  39936
#define SSS  60416
#define SOW  61440
#define S_LDS 66560

// ---------------- K1: W-blocks (0..191) compute w2t; G-blocks (192..1727) do GEMM1+epilogue.
// G-block = (b, slab of 32 t-rows). 192 threads = 3 waves; wave nt owns matrix nt (k/v/r).
// x staged once (33 contiguous rows) into swizzled bf16 LDS; weights live in 64 VGPRs/wave.
__global__ __launch_bounds__(192, 3) void k1_kernel(
    const float* __restrict__ x,
    const float* __restrict__ time_w,
    const float* __restrict__ time_alpha,
    const float* __restrict__ time_beta,
    const float* __restrict__ key_w,  const float* __restrict__ key_b,
    const float* __restrict__ value_w,const float* __restrict__ value_b,
    const float* __restrict__ recep_w,const float* __restrict__ recep_b,
    char* __restrict__ ws)
{
    __shared__ __align__(16) char smem[33792];
    const int tid = threadIdx.x;
    __bf16* w2t = (__bf16*)(ws + W2T_WS);
    int blk = blockIdx.x;

    if (blk < 192) {
        // ---- W path: w2t[t][s] = beta[s,t] * sum_{u<=t} tw[s,255+u-t]*alpha[s,u]
        const int s = blk;
        if (s >= S_LEN) {
            for (int t = tid; t < 256; t += 192) w2t[t * SP + s] = (__bf16)0.f;
            return;
        }
        float* tw = (float*)smem;            // [256]
        float* al = (float*)(smem + 1024);   // [256]
        for (int i = tid; i < 256; i += 192) {
            tw[i] = time_w[s * 256 + i];
            al[i] = time_alpha[s * 256 + i];
        }
        __syncthreads();
        for (int t = tid; t < 256; t += 192) {
            float acc = 0.f;
            for (int u = 0; u <= t; ++u)
                acc = fmaf(tw[255 + u - t], al[u], acc);
            w2t[t * SP + s] = (__bf16)(time_beta[s * 256 + t] * acc);
        }
        return;
    }

    // ---- G path
    blk -= 192;
    const int b    = blk / 6;
    const int slab = blk - b * 6;
    const int t0   = slab * 32;
    const int lane = tid & 63;
    const int wv   = tid >> 6;       // 0..2 -> key/value/recep
    const int q    = lane >> 4;
    const int hs   = lane & 15;
    const float* xb = x + (size_t)b * (S_LEN * 512);

    // stage x rows t0-1 .. t0+31 (33 rows, contiguous 2 KB each) as swizzled bf16
    #pragma unroll 4
    for (int u = 0; u < 22; ++u) {
        int i   = tid + u * 192;     // 0..4223 (33 rows * 128 float4)
        int row = i >> 7;
        int cu  = i & 127;
        int g   = t0 - 1 + row;
        float4 f = {0.f, 0.f, 0.f, 0.f};
        if (g >= 0 && g < S_LEN) f = *(const float4*)(xb + (size_t)g * 512 + cu * 4);
        bf16x4 p;
        p[0] = (__bf16)f.x; p[1] = (__bf16)f.y; p[2] = (__bf16)f.z; p[3] = (__bf16)f.w;
        u32 off = ((u32)row << 10) + ((((u32)cu) << 3) ^ (((u32)(row & 7)) << 4));
        *(bf16x4*)(smem + off) = p;
    }

    // B-fragments: wave's matrix rows [16][512] f32 -> 16 x bf16x8 (64 VGPR)
    const float* wmat = (wv == 0) ? key_w : (wv == 1) ? value_w : recep_w;
    const float* bvec = (wv == 0) ? key_b : (wv == 1) ? value_b : recep_b;
    bf16x8 bfrag[16];
    #pragma unroll
    for (int ksb = 0; ksb < 16; ksb += 4) {
        float4 w0[4], w1[4];
        #pragma unroll
        for (int j = 0; j < 4; ++j) {
            const float* src = wmat + hs * 512 + (ksb + j) * 32 + q * 8;
            w0[j] = *(const float4*)src;
            w1[j] = *(const float4*)(src + 4);
        }
        #pragma unroll
        for (int j = 0; j < 4; ++j) {
            bf16x8 p;
            p[0]=(__bf16)w0[j].x; p[1]=(__bf16)w0[j].y; p[2]=(__bf16)w0[j].z; p[3]=(__bf16)w0[j].w;
            p[4]=(__bf16)w1[j].x; p[5]=(__bf16)w1[j].y; p[6]=(__bf16)w1[j].z; p[7]=(__bf16)w1[j].w;
            bfrag[ksb + j] = p;
        }
    }
    __syncthreads();

    // MFMA: M=32 (2 m-tiles), N=16 (this wave's matrix), K=512.
    // k-cols < 256 use LDS row lt (global t-1: channel shift); cols >= 256 use row lt+1.
    f32x4 acc0 = (f32x4){0.f,0.f,0.f,0.f};
    f32x4 acc1 = (f32x4){0.f,0.f,0.f,0.f};
    #pragma unroll
    for (int ks = 0; ks < 16; ++ks) {
        u32 colb = ((u32)(ks * 32 + q * 8)) << 1;
        int r0 = hs + ((ks < 8) ? 0 : 1);
        u32 off0 = ((u32)r0 << 10) + (colb ^ (((u32)(r0 & 7)) << 4));
        bf16x8 a0 = *(const bf16x8*)(smem + off0);
        acc0 = __builtin_amdgcn_mfma_f32_16x16x32_bf16(a0, bfrag[ks], acc0, 0, 0, 0);
        int r1 = r0 + 16;
        u32 off1 = ((u32)r1 << 10) + (colb ^ (((u32)(r1 & 7)) << 4));
        bf16x8 a1 = *(const bf16x8*)(smem + off1);
        acc1 = __builtin_amdgcn_mfma_f32_16x16x32_bf16(a1, bfrag[ks], acc1, 0, 0, 0);
    }
    __syncthreads();   // xtile dead; reuse LDS for raw results

    // epilogue stage 1: raw GEMM outputs (+bias) -> LDS [3][32][16] f32
    float* raw = (float*)smem;
    const float bias = bvec[hs];
    #pragma unroll
    for (int m = 0; m < 2; ++m) {
        f32x4 A = m ? acc1 : acc0;
        #pragma unroll
        for (int rg = 0; rg < 4; ++rg) {
            int lt = m * 16 + q * 4 + rg;
            raw[wv * 512 + lt * 16 + hs] = A[rg] + bias;
        }
    }
    __syncthreads();

    // epilogue stage 2: ke = exp(clip(k)), kv = ke*v, sg = sigmoid(r) -> ws
    float* keg = (float*)(ws + KE_WS);
    float* kvg = (float*)(ws + KV_WS);
    float* sgg = (float*)(ws + SG_WS);
    #pragma unroll
    for (int u = 0; u < 3; ++u) {
        int i = tid + u * 192;
        if (i < 512) {
            int lt = i >> 4, h = i & 15;
            int t = t0 + lt;
            if (t < S_LEN) {
                float kk = fminf(fmaxf(raw[i], -60.f), 30.f);
                float ke = __expf(kk);
                size_t o = ((size_t)b * 176 + t) * 16 + h;
                keg[o] = ke;
                kvg[o] = ke * raw[512 + i];
                sgg[o] = 1.f / (1.f + __expf(-raw[1024 + i]));
            }
        }
    }
}

// ---------------- kernel S: scan + wkv + out-proj. 256 blocks (one per b)
__global__ __launch_bounds__(256) void scan_kernel(
    const char* __restrict__ wsr,
    const float* __restrict__ out_w, const float* __restrict__ out_b,
    const float* __restrict__ gamma,
    float* __restrict__ out)
{
    __shared__ __align__(16) char smem[S_LDS];
    const int tid  = threadIdx.x;
    const int lane = tid & 63;
    const int wid  = tid >> 6;      // 0..3
    const int q    = lane >> 4;
    const int hs   = lane & 15;
    const int b    = blockIdx.x;
    const __bf16* w2t = (const __bf16*)(wsr + W2T_WS);
    const float4* keb = (const float4*)(wsr + KE_WS + (size_t)b * 11264);
    const float4* kvb = (const float4*)(wsr + KV_WS + (size_t)b * 11264);
    const float4* sgb = (const float4*)(wsr + SG_WS + (size_t)b * 11264);

    #pragma unroll
    for (int it = 0; it < 3; ++it) {
        int i = tid + (it << 8);
        if (i < 676) {
            ((float4*)(smem + SKE))[i] = keb[i];
            ((float4*)(smem + SKV))[i] = kvb[i];
            ((float4*)(smem + SG2))[i] = sgb[i];
        }
    }
    for (int i = tid; i < 2560; i += 256) {
        int o = i / 40, c = i - o * 40;
        ((__bf16*)(smem + SOW))[i] = (c < 16) ? (__bf16)out_w[o * 16 + c] : (__bf16)0.f;
    }
    for (int i = tid; i < 4096; i += 256) {
        int row = i >> 4, c = 16 + (i & 15);
        ((__bf16*)(smem + SRB))[row * 40 + c] = (__bf16)0.f;
    }
    for (int i = tid; i < 368; i += 256) {
        int h2 = i & 15; int t = S_LEN + (i >> 4);
        u32 off = ((u32)(h2 * 384 + t * 2)) ^ (((u32)(h2 & 7)) << 4);
        *(__bf16*)(smem + SKVT + off) = (__bf16)0.f;
    }
    __syncthreads();

    float* KE = (float*)(smem + SKE);
    float* KV = (float*)(smem + SKV);
    float* GG = (float*)(smem + SG2);
    float* SEG = (float*)(smem + SSS);
    const int h  = tid & 15;
    const int sg = tid >> 4;
    const int ts = sg * 11;
    const int te = (ts + 11 < S_LEN) ? ts + 11 : S_LEN;
    {
        float ssum = 0.f;
        for (int t = ts; t < te; ++t) ssum += KE[t * 16 + h];
        SEG[sg * 16 + h] = ssum;
    }
    __syncthreads();
    {
        float run = 0.f;
        for (int s2 = 0; s2 < sg; ++s2) run += SEG[s2 * 16 + h];
        for (int t = ts; t < te; ++t) {
            run += KE[t * 16 + h];
            u32 off = ((u32)(h * 384 + t * 2)) ^ (((u32)(h & 7)) << 4);
            *(__bf16*)(smem + SKVT + off) = (__bf16)KV[t * 16 + h];
            GG[t * 16 + h] = GG[t * 16 + h] / run;
        }
    }
    __syncthreads();

    // wkv: [256 t] x [192 s] @ [192 s][16 c]; A-frags from global w2t (L2-hot)
    f32x4 wa[4];
    #pragma unroll
    for (int mi = 0; mi < 4; ++mi) wa[mi] = (f32x4){0.f,0.f,0.f,0.f};
    #pragma unroll
    for (int s0 = 0; s0 < SP; s0 += 32) {
        int scol = s0 + (q << 3);
        u32 boff = ((u32)(hs * 384 + scol * 2)) ^ (((u32)(hs & 7)) << 4);
        bf16x8 bfr = *(const bf16x8*)(smem + SKVT + boff);
        #pragma unroll
        for (int mi = 0; mi < 4; ++mi) {
            int row = (wid + (mi << 2)) * 16 + hs;
            bf16x8 afr = *(const bf16x8*)(w2t + row * SP + scol);
            wa[mi] = __builtin_amdgcn_mfma_f32_16x16x32_bf16(afr, bfr, wa[mi], 0,0,0);
        }
    }
    #pragma unroll
    for (int mi = 0; mi < 4; ++mi) {
        int tb = (wid + (mi << 2)) * 16 + (q << 2);
        #pragma unroll
        for (int rg = 0; rg < 4; ++rg) {
            int t = tb + rg;
            float fac = (t < S_LEN) ? GG[t * 16 + hs] : 0.5f;
            ((__bf16*)(smem + SRB))[t * 40 + hs] = (__bf16)(wa[mi][rg] * fac);
        }
    }
    __syncthreads();

    float obv[4];
    #pragma unroll
    for (int nt = 0; nt < 4; ++nt) obv[nt] = out_b[nt * 16 + hs];
    #pragma unroll
    for (int mi = 0; mi < 4; ++mi) {
        int mt = wid + (mi << 2);
        int arow = mt * 16 + hs;
        bf16x8 afr = *(const bf16x8*)(smem + SRB + (u32)(arow * 80 + (q << 4)));
        float gm[4];
        #pragma unroll
        for (int rg = 0; rg < 4; ++rg) gm[rg] = gamma[mt * 16 + (q << 2) + rg];
        #pragma unroll
        for (int nt = 0; nt < 4; ++nt) {
            int orow = nt * 16 + hs;
            bf16x8 bfr = *(const bf16x8*)(smem + SOW + (u32)(orow * 80 + (q << 4)));
            f32x4 zc = (f32x4){0.f,0.f,0.f,0.f};
            f32x4 d = __builtin_amdgcn_mfma_f32_16x16x32_bf16(afr, bfr, zc, 0,0,0);
            #pragma unroll
            for (int rg = 0; rg < 4; ++rg) {
                int t = mt * 16 + (q << 2) + rg;
                out[(size_t)b * 16384 + (size_t)t * 64 + nt * 16 + hs] = (d[rg] + obv[nt]) * gm[rg];
            }
        }
    }
}

extern "C" void kernel_launch(void* const* d_in, const int* in_sizes, int n_in,
                              void* d_out, int out_size, void* d_ws, size_t ws_size,
                              hipStream_t stream) {
    const float* x          = (const float*)d_in[0];
    const float* time_w     = (const float*)d_in[1];
    const float* time_alpha = (const float*)d_in[2];
    const float* time_beta  = (const float*)d_in[3];
    const float* time_gamma = (const float*)d_in[4];
    const float* key_w      = (const float*)d_in[5];
    const float* key_b      = (const float*)d_in[6];
    const float* value_w    = (const float*)d_in[7];
    const float* value_b    = (const float*)d_in[8];
    const float* recep_w    = (const float*)d_in[9];
    const float* recep_b    = (const float*)d_in[10];
    const float* out_w      = (const float*)d_in[11];
    const float* out_b      = (const float*)d_in[12];
    char* ws = (char*)d_ws;

    k1_kernel<<<1728, 192, 0, stream>>>(x, time_w, time_alpha, time_beta,
                                        key_w, key_b, value_w, value_b,
                                        recep_w, recep_b, ws);
    scan_kernel<<<256, 256, 0, stream>>>(ws, out_w, out_b, time_gamma, (float*)d_out);
}

// Round 6
// 41.098 us; speedup vs baseline: 1.3592x; 1.3592x over previous
//
#include <hip/hip_runtime.h>

typedef unsigned short u16;
typedef unsigned int u32;
typedef __attribute__((ext_vector_type(8))) __bf16 bf16x8;
typedef __attribute__((ext_vector_type(4))) __bf16 bf16x4;
typedef __attribute__((ext_vector_type(4))) float f32x4;

#define S_LEN 169
#define SP 192

// ---------------- workspace layout (bytes)
#define W2T_WS 0                          // bf16 [256][192] = 98304
#define WPK_WS 98304                      // bf16 frag-packed [3][16][64][16B] = 49152
#define KE_WS  147456                     // f32 [256][176][16] = 2883584
#define KV_WS  (147456 + 2883584)
#define SG_WS  (147456 + 2 * 2883584)

// ---------------- G kernel LDS (48 KB -> 3 blocks/CU)
#define F32A 0
#define F32B 16384
#define BFA  32768
#define BFB  40960
#define G_LDS 49152

// ---------------- S kernel LDS
#define SKE  0
#define SKV  11264
#define SG2  22528
#define SKVT 33792
#define SRB  39936
#define SSS  60416
#define SOW  61440
#define S_LDS 66560

// ---------------- K0: blocks 0..191 compute w2t; blocks 192..194 pack weights
__global__ __launch_bounds__(1024) void k0_kernel(
    const float* __restrict__ time_w,
    const float* __restrict__ time_alpha,
    const float* __restrict__ time_beta,
    const float* __restrict__ key_w,
    const float* __restrict__ value_w,
    const float* __restrict__ recep_w,
    char* __restrict__ ws)
{
    __bf16* w2t = (__bf16*)(ws + W2T_WS);
    const int blk = blockIdx.x;
    if (blk >= 192) {
        // pack matrix m into MFMA B-frag order: frag fid=(ks,l): W[l&15][ks*32+(l>>4)*8 ..+8]
        const int m = blk - 192;
        const float* wmat = (m == 0) ? key_w : (m == 1) ? value_w : recep_w;
        const int g = threadIdx.x;           // granule: 8 consecutive f32, coalesced read
        const float* src = wmat + g * 8;
        float4 f0 = *(const float4*)src;
        float4 f1 = *(const float4*)(src + 4);
        bf16x8 p;
        p[0]=(__bf16)f0.x; p[1]=(__bf16)f0.y; p[2]=(__bf16)f0.z; p[3]=(__bf16)f0.w;
        p[4]=(__bf16)f1.x; p[5]=(__bf16)f1.y; p[6]=(__bf16)f1.z; p[7]=(__bf16)f1.w;
        int hs = g >> 6, rem = g & 63, ks = rem >> 2, q = rem & 3;
        int fid = ks * 64 + q * 16 + hs;
        *(bf16x8*)(ws + WPK_WS + m * 16384 + fid * 16) = p;
        return;
    }
    __shared__ float tw[256];
    __shared__ float al[256];
    __shared__ float part[4][256];
    const int s = blk;
    const int t = threadIdx.x & 255;
    const int p = threadIdx.x >> 8;
    if (s >= S_LEN) {
        if (p == 0) w2t[t * SP + s] = (__bf16)0.f;
        return;
    }
    if (p == 0) { tw[t] = time_w[s * 256 + t]; al[t] = time_alpha[s * 256 + t]; }
    __syncthreads();
    const int u0 = p << 6;
    const int u1 = (u0 + 64 < t + 1) ? (u0 + 64) : (t + 1);
    float acc = 0.f;
    for (int u = u0; u < u1; ++u)
        acc = fmaf(tw[255 + u - t], al[u], acc);
    part[p][t] = acc;
    __syncthreads();
    if (p == 0)
        w2t[t * SP + s] = (__bf16)(time_beta[s * 256 + t] *
                                   (part[0][t] + part[1][t] + part[2][t] + part[3][t]));
}

// ---------------- G: GEMM1 + pointwise. 768 blocks = (b, slab of 64 t-rows), 256 thr.
__global__ __launch_bounds__(256, 3) void g_kernel(
    const float* __restrict__ x,
    const float* __restrict__ key_b,
    const float* __restrict__ value_b,
    const float* __restrict__ recep_b,
    char* __restrict__ ws)
{
    __shared__ __align__(16) char smem[G_LDS];
    const int tid  = threadIdx.x;
    const int lane = tid & 63;
    const int wid  = tid >> 6;       // 0..3; waves 0-2 = matrices k/v/r, wave 3 = helper
    const int q    = lane >> 4;
    const int hs   = lane & 15;
    const int blk  = blockIdx.x;
    const int b    = blk / 3;
    const int slab = blk - b * 3;
    const int t0   = slab * 64;
    const int rquad = wid * 4 + (lane >> 4);   // row-quarter for staging
    const int col4  = lane & 15;
    const float* xb = x + (size_t)b * (S_LEN * 512);

    // B-fragments from pre-packed ws: 16 coalesced 1 KB wave-loads, L2-hot
    bf16x8 bfrag[16];
    if (wid < 3) {
        #pragma unroll
        for (int ks = 0; ks < 16; ++ks)
            bfrag[ks] = *(const bf16x8*)(ws + WPK_WS + wid * 16384 + (ks * 64 + lane) * 16);
    }

    // async stage of chunk c (64 rows x 64 f32 cols) into f32 LDS buf: 4 gl_lds per thread
    auto issue = [&](int c, u32 fbuf) {
        const int row_base = (c < 4) ? (t0 - 1) : t0;   // channel shift on first half
        #pragma unroll
        for (int it = 0; it < 4; ++it) {
            int row = it * 16 + rquad;
            int rg  = row_base + row;
            int grc = rg < 0 ? 0 : (rg > S_LEN - 1 ? S_LEN - 1 : rg);   // clamp: load stays unconditional
            const float* src = xb + (size_t)grc * 512 + c * 64 + col4 * 4;
            void* ldst = (void*)(smem + fbuf + it * 4096 + wid * 1024);  // wave-uniform base
            __builtin_amdgcn_global_load_lds((const __attribute__((address_space(1))) void*)src,
                                             (__attribute__((address_space(3))) void*)ldst,
                                             16, 0, 0);
        }
    };

    // thread-local f32 LDS -> cvt -> swizzled bf16 tile (invalid rows -> 0)
    auto cvtphase = [&](int c, u32 fbuf, u32 bbuf) {
        const int row_base = (c < 4) ? (t0 - 1) : t0;
        #pragma unroll
        for (int it = 0; it < 4; ++it) {
            int u   = it * 256 + tid;
            int row = u >> 4;
            f32x4 f = *(const f32x4*)(smem + fbuf + (u32)u * 16);
            int rg = row_base + row;
            if ((unsigned)rg >= (unsigned)S_LEN) f = (f32x4){0.f, 0.f, 0.f, 0.f};
            bf16x4 p;
            p[0] = (__bf16)f[0]; p[1] = (__bf16)f[1]; p[2] = (__bf16)f[2]; p[3] = (__bf16)f[3];
            u32 off = (u32)row * 128 + ((((u32)u & 15u) * 8u) ^ (((u32)row & 7u) << 4));
            *(bf16x4*)(smem + bbuf + off) = p;
        }
    };

    f32x4 acc[4];
    #pragma unroll
    for (int mt = 0; mt < 4; ++mt) acc[mt] = (f32x4){0.f, 0.f, 0.f, 0.f};

    auto mfmaphase = [&](int c, u32 bbuf) {
        if (wid < 3) {
            #pragma unroll
            for (int s = 0; s < 2; ++s) {
                #pragma unroll
                for (int mt = 0; mt < 4; ++mt) {
                    int r = mt * 16 + hs;
                    u32 off = (u32)r * 128 + (((u32)(64 * s + 16 * q)) ^ (((u32)r & 7u) << 4));
                    bf16x8 a = *(const bf16x8*)(smem + bbuf + off);
                    acc[mt] = __builtin_amdgcn_mfma_f32_16x16x32_bf16(a, bfrag[c * 2 + s], acc[mt], 0, 0, 0);
                }
            }
        }
    };

#define PERIOD(c, VMN) do {                                         \
    asm volatile("s_waitcnt vmcnt(" #VMN ")" ::: "memory");         \
    cvtphase(c, ((c) & 1) ? F32B : F32A, ((c) & 1) ? BFB : BFA);    \
    asm volatile("s_waitcnt lgkmcnt(0)" ::: "memory");              \
    if ((c) + 2 < 8) issue((c) + 2, ((c) & 1) ? F32B : F32A);       \
    asm volatile("s_barrier" ::: "memory");                         \
    mfmaphase(c, ((c) & 1) ? BFB : BFA);                            \
} while (0)

    issue(0, F32A);
    issue(1, F32B);
    PERIOD(0, 4); PERIOD(1, 4); PERIOD(2, 4); PERIOD(3, 4);
    PERIOD(4, 4); PERIOD(5, 4); PERIOD(6, 4); PERIOD(7, 0);
#undef PERIOD

    // epilogue: raw acc (+bias) -> LDS [3][64][16] f32, then combine -> ws
    float* raw = (float*)(smem + F32A);
    if (wid < 3) {
        const float* bv = (wid == 0) ? key_b : (wid == 1) ? value_b : recep_b;
        const float bias = bv[hs];
        #pragma unroll
        for (int mt = 0; mt < 4; ++mt) {
            #pragma unroll
            for (int rg = 0; rg < 4; ++rg) {
                int tl = mt * 16 + q * 4 + rg;
                raw[wid * 1024 + tl * 16 + hs] = acc[mt][rg] + bias;
            }
        }
    }
    __syncthreads();
    float* keg = (float*)(ws + KE_WS);
    float* kvg = (float*)(ws + KV_WS);
    float* sgg = (float*)(ws + SG_WS);
    #pragma unroll
    for (int it = 0; it < 4; ++it) {
        int i  = it * 256 + tid;
        int tl = i >> 4, h = i & 15;
        int t  = t0 + tl;
        if (t < S_LEN) {
            float kk = fminf(fmaxf(raw[i], -60.f), 30.f);
            float ke = __expf(kk);
            size_t o = ((size_t)b * 176 + t) * 16 + h;
            keg[o] = ke;
            kvg[o] = ke * raw[1024 + i];
            sgg[o] = 1.f / (1.f + __expf(-raw[2048 + i]));
        }
    }
}

// ---------------- kernel S: scan + wkv + out-proj. 256 blocks (one per b)
__global__ __launch_bounds__(256) void scan_kernel(
    const char* __restrict__ wsr,
    const float* __restrict__ out_w, const float* __restrict__ out_b,
    const float* __restrict__ gamma,
    float* __restrict__ out)
{
    __shared__ __align__(16) char smem[S_LDS];
    const int tid  = threadIdx.x;
    const int lane = tid & 63;
    const int wid  = tid >> 6;
    const int q    = lane >> 4;
    const int hs   = lane & 15;
    const int b    = blockIdx.x;
    const __bf16* w2t = (const __bf16*)(wsr + W2T_WS);
    const float4* keb = (const float4*)(wsr + KE_WS + (size_t)b * 11264);
    const float4* kvb = (const float4*)(wsr + KV_WS + (size_t)b * 11264);
    const float4* sgb = (const float4*)(wsr + SG_WS + (size_t)b * 11264);

    #pragma unroll
    for (int it = 0; it < 3; ++it) {
        int i = tid + (it << 8);
        if (i < 676) {
            ((float4*)(smem + SKE))[i] = keb[i];
            ((float4*)(smem + SKV))[i] = kvb[i];
            ((float4*)(smem + SG2))[i] = sgb[i];
        }
    }
    for (int i = tid; i < 2560; i += 256) {
        int o = i / 40, c = i - o * 40;
        ((__bf16*)(smem + SOW))[i] = (c < 16) ? (__bf16)out_w[o * 16 + c] : (__bf16)0.f;
    }
    for (int i = tid; i < 4096; i += 256) {
        int row = i >> 4, c = 16 + (i & 15);
        ((__bf16*)(smem + SRB))[row * 40 + c] = (__bf16)0.f;
    }
    for (int i = tid; i < 368; i += 256) {
        int h2 = i & 15; int t = S_LEN + (i >> 4);
        u32 off = ((u32)(h2 * 384 + t * 2)) ^ (((u32)(h2 & 7)) << 4);
        *(__bf16*)(smem + SKVT + off) = (__bf16)0.f;
    }
    __syncthreads();

    float* KE = (float*)(smem + SKE);
    float* KV = (float*)(smem + SKV);
    float* GG = (float*)(smem + SG2);
    float* SEG = (float*)(smem + SSS);
    const int h  = tid & 15;
    const int sg = tid >> 4;
    const int ts = sg * 11;
    const int te = (ts + 11 < S_LEN) ? ts + 11 : S_LEN;
    {
        float ssum = 0.f;
        for (int t = ts; t < te; ++t) ssum += KE[t * 16 + h];
        SEG[sg * 16 + h] = ssum;
    }
    __syncthreads();
    {
        float run = 0.f;
        for (int s2 = 0; s2 < sg; ++s2) run += SEG[s2 * 16 + h];
        for (int t = ts; t < te; ++t) {
            run += KE[t * 16 + h];
            u32 off = ((u32)(h * 384 + t * 2)) ^ (((u32)(h & 7)) << 4);
            *(__bf16*)(smem + SKVT + off) = (__bf16)KV[t * 16 + h];
            GG[t * 16 + h] = GG[t * 16 + h] / run;
        }
    }
    __syncthreads();

    f32x4 wa[4];
    #pragma unroll
    for (int mi = 0; mi < 4; ++mi) wa[mi] = (f32x4){0.f,0.f,0.f,0.f};
    #pragma unroll
    for (int s0 = 0; s0 < SP; s0 += 32) {
        int scol = s0 + (q << 3);
        u32 boff = ((u32)(hs * 384 + scol * 2)) ^ (((u32)(hs & 7)) << 4);
        bf16x8 bfr = *(const bf16x8*)(smem + SKVT + boff);
        #pragma unroll
        for (int mi = 0; mi < 4; ++mi) {
            int row = (wid + (mi << 2)) * 16 + hs;
            bf16x8 afr = *(const bf16x8*)(w2t + row * SP + scol);
            wa[mi] = __builtin_amdgcn_mfma_f32_16x16x32_bf16(afr, bfr, wa[mi], 0,0,0);
        }
    }
    #pragma unroll
    for (int mi = 0; mi < 4; ++mi) {
        int tb = (wid + (mi << 2)) * 16 + (q << 2);
        #pragma unroll
        for (int rg = 0; rg < 4; ++rg) {
            int t = tb + rg;
            float fac = (t < S_LEN) ? GG[t * 16 + hs] : 0.5f;
            ((__bf16*)(smem + SRB))[t * 40 + hs] = (__bf16)(wa[mi][rg] * fac);
        }
    }
    __syncthreads();

    float obv[4];
    #pragma unroll
    for (int nt = 0; nt < 4; ++nt) obv[nt] = out_b[nt * 16 + hs];
    #pragma unroll
    for (int mi = 0; mi < 4; ++mi) {
        int mt = wid + (mi << 2);
        int arow = mt * 16 + hs;
        bf16x8 afr = *(const bf16x8*)(smem + SRB + (u32)(arow * 80 + (q << 4)));
        float gm[4];
        #pragma unroll
        for (int rg = 0; rg < 4; ++rg) gm[rg] = gamma[mt * 16 + (q << 2) + rg];
        #pragma unroll
        for (int nt = 0; nt < 4; ++nt) {
            int orow = nt * 16 + hs;
            bf16x8 bfr = *(const bf16x8*)(smem + SOW + (u32)(orow * 80 + (q << 4)));
            f32x4 zc = (f32x4){0.f,0.f,0.f,0.f};
            f32x4 d = __builtin_amdgcn_mfma_f32_16x16x32_bf16(afr, bfr, zc, 0,0,0);
            #pragma unroll
            for (int rg = 0; rg < 4; ++rg) {
                int t = mt * 16 + (q << 2) + rg;
                out[(size_t)b * 16384 + (size_t)t * 64 + nt * 16 + hs] = (d[rg] + obv[nt]) * gm[rg];
            }
        }
    }
}

extern "C" void kernel_launch(void* const* d_in, const int* in_sizes, int n_in,
                              void* d_out, int out_size, void* d_ws, size_t ws_size,
                              hipStream_t stream) {
    const float* x          = (const float*)d_in[0];
    const float* time_w     = (const float*)d_in[1];
    const float* time_alpha = (const float*)d_in[2];
    const float* time_beta  = (const float*)d_in[3];
    const float* time_gamma = (const float*)d_in[4];
    const float* key_w      = (const float*)d_in[5];
    const float* key_b      = (const float*)d_in[6];
    const float* value_w    = (const float*)d_in[7];
    const float* value_b    = (const float*)d_in[8];
    const float* recep_w    = (const float*)d_in[9];
    const float* recep_b    = (const float*)d_in[10];
    const float* out_w      = (const float*)d_in[11];
    const float* out_b      = (const float*)d_in[12];
    char* ws = (char*)d_ws;

    k0_kernel<<<195, 1024, 0, stream>>>(time_w, time_alpha, time_beta,
                                        key_w, value_w, recep_w, ws);
    g_kernel<<<768, 256, 0, stream>>>(x, key_b, value_b, recep_b, ws);
    scan_kernel<<<256, 256, 0, stream>>>(ws, out_w, out_b, time_gamma, (float*)d_out);
}